// Round 3
// baseline (76.338 us; speedup 1.0000x reference)
//
#include <hip/hip_runtime.h>
#include <hip/hip_bf16.h>

#define N_NODES 207
#define N_EDGES 1722
#define BATCH   64
#define BLOCK   256

#define EPT       4                       // edges per vector load
#define NVEC      (N_EDGES / EPT)         // 430 full int4/float4 vectors
#define VEC_EDGES (NVEC * EPT)            // 1720
#define TAIL      (N_EDGES - VEC_EDGES)   // 2
#define NITER     ((NVEC + BLOCK - 1) / BLOCK)  // 2

// One block per batch row; Laplacians never materialized:
//   reaction[b,n] = in[b,n]*csr[n] - sum_{k: i_k=n} w_r[k]*in[b,j_k] + bias_r[n]
//   csr[c]        = sum_{k: j_k=c} w_r[k]
//   diffusion[b,n]= in[b,n]*csd[n] - sum_{k: j_k=n} w_d[k]*in[b,i_k] + bias_d[n]
//   csd[c]        = sum_{k: i_k=c} w_d[k]
//   out = tanh(reaction) + diffusion + in
// Edge/weight global loads are issued FIRST (independent of s_in) so their
// L2/HBM latency hides behind LDS staging + barrier.
__global__ __launch_bounds__(BLOCK) void reaction_diffusion_kernel(
    const float* __restrict__ input,    // [B, N]
    const float* __restrict__ w_r,      // [E]
    const float* __restrict__ w_d,      // [E]
    const float* __restrict__ bias_r,   // [N]
    const float* __restrict__ bias_d,   // [N]
    const int* __restrict__ edge_i,     // [E]
    const int* __restrict__ edge_j,     // [E]
    float* __restrict__ out)            // [B, N]
{
    __shared__ float s_in[N_NODES];
    __shared__ float s_reac[N_NODES];
    __shared__ float s_diff[N_NODES];
    __shared__ float s_csr[N_NODES];
    __shared__ float s_csd[N_NODES];

    const int b   = blockIdx.x;
    const int tid = threadIdx.x;

    // ---- 1. Issue edge/weight loads into registers (latency overlaps staging) ----
    int4   vi[NITER], vj[NITER];
    float4 vr[NITER], vd[NITER];
    bool   vvalid[NITER];
    #pragma unroll
    for (int it = 0; it < NITER; ++it) {
        const int v = tid + it * BLOCK;
        vvalid[it] = (v < NVEC);
        if (vvalid[it]) {
            vi[it] = ((const int4*)edge_i)[v];
            vj[it] = ((const int4*)edge_j)[v];
            vr[it] = ((const float4*)w_r)[v];
            vd[it] = ((const float4*)w_d)[v];
        }
    }
    int   ti = 0, tj = 0;
    float tr = 0.0f, td = 0.0f;
    const bool has_tail = (tid < TAIL);
    if (has_tail) {
        ti = edge_i[VEC_EDGES + tid];
        tj = edge_j[VEC_EDGES + tid];
        tr = w_r[VEC_EDGES + tid];
        td = w_d[VEC_EDGES + tid];
    }

    // ---- 2. Stage input row + zero accumulators ----
    for (int n = tid; n < N_NODES; n += BLOCK) {
        s_in[n]   = input[b * N_NODES + n];
        s_reac[n] = 0.0f;
        s_diff[n] = 0.0f;
        s_csr[n]  = 0.0f;
        s_csd[n]  = 0.0f;
    }
    __syncthreads();

    // ---- 3. Scatter edge contributions (LDS atomics, avg degree ~8) ----
    #pragma unroll
    for (int it = 0; it < NITER; ++it) {
        if (vvalid[it]) {
            const int*   pi = &vi[it].x;
            const int*   pj = &vj[it].x;
            const float* pr = &vr[it].x;
            const float* pd = &vd[it].x;
            #pragma unroll
            for (int e = 0; e < EPT; ++e) {
                atomicAdd(&s_reac[pi[e]], pr[e] * s_in[pj[e]]);
                atomicAdd(&s_csr[pj[e]],  pr[e]);
                atomicAdd(&s_diff[pj[e]], pd[e] * s_in[pi[e]]);
                atomicAdd(&s_csd[pi[e]],  pd[e]);
            }
        }
    }
    if (has_tail) {
        atomicAdd(&s_reac[ti], tr * s_in[tj]);
        atomicAdd(&s_csr[tj],  tr);
        atomicAdd(&s_diff[tj], td * s_in[ti]);
        atomicAdd(&s_csd[ti],  td);
    }
    __syncthreads();

    // ---- 4. Epilogue: fast branchless tanh + combine ----
    for (int n = tid; n < N_NODES; n += BLOCK) {
        const float x = s_in[n];
        const float r = x * s_csr[n] - s_reac[n] + bias_r[n];
        const float d = x * s_csd[n] - s_diff[n] + bias_d[n];
        // tanh(r) = sign(r) * (1 - e) / (1 + e), e = exp(-2|r|); stable for all r
        const float ar = fabsf(r);
        const float e  = __expf(-2.0f * ar);
        const float t  = (1.0f - e) / (1.0f + e);
        const float th = copysignf(t, r);
        out[b * N_NODES + n] = th + d + x;
    }
}

extern "C" void kernel_launch(void* const* d_in, const int* in_sizes, int n_in,
                              void* d_out, int out_size, void* d_ws, size_t ws_size,
                              hipStream_t stream) {
    const float* input  = (const float*)d_in[0];
    const float* w_r    = (const float*)d_in[1];
    const float* w_d    = (const float*)d_in[2];
    const float* bias_r = (const float*)d_in[3];
    const float* bias_d = (const float*)d_in[4];
    const int*   edge_i = (const int*)d_in[5];
    const int*   edge_j = (const int*)d_in[6];
    float*       out    = (float*)d_out;

    reaction_diffusion_kernel<<<BATCH, BLOCK, 0, stream>>>(
        input, w_r, w_d, bias_r, bias_d, edge_i, edge_j, out);
}